// Round 12
// baseline (296.405 us; speedup 1.0000x reference)
//
#include <hip/hip_runtime.h>
#include <stdint.h>

// Problem constants (fixed by the reference)
#define NQ 2048
#define NK 4096
#define DFF 2048
#define SPLITS 8

using u16 = unsigned short;
typedef float f32x4 __attribute__((ext_vector_type(4)));
typedef short s16x8 __attribute__((ext_vector_type(8)));
typedef __attribute__((address_space(3))) void as3_void;
typedef __attribute__((address_space(1))) void as1_void;

__device__ __forceinline__ u16 f2h(float f) {           // fp32 -> fp16 bits (RNE)
  _Float16 h = (_Float16)f;
  return __builtin_bit_cast(u16, h);
}
__device__ __forceinline__ float h2f(u16 u) {
  return (float)__builtin_bit_cast(_Float16, u);
}
__device__ __forceinline__ void mfma16h(f32x4& d, s16x8 a, s16x8 b) {  // fp16
  asm volatile("v_mfma_f32_16x16x32_f16 %0, %1, %2, %0" : "+v"(d) : "v"(a), "v"(b));
}
// async global->LDS DMA, 16B/lane; LDS dest = wave-uniform base + lane*16.
__device__ __forceinline__ void gll16(const void* g, const void* l) {
  uint32_t off = (uint32_t)(uintptr_t)l;
  off = (uint32_t)__builtin_amdgcn_readfirstlane((int)off);
  __builtin_amdgcn_global_load_lds((const as1_void*)(uintptr_t)g,
                                   (as3_void*)(uintptr_t)off, 16, 0, 0);
}

// ---------------------------------------------------------------------------
// int64-vs-int32 detector for index inputs.
// ---------------------------------------------------------------------------
__global__ void detect_i64_kernel(const int* __restrict__ IP, int* __restrict__ flag) {
  if (threadIdx.x == 0 && blockIdx.x == 0) {
    int f = 1;
    for (int j = 1; j < 128; j += 2) f &= (IP[j] == 0);
    *flag = f;
  }
}

// fp32 -> fp16 single-plane quantizer (FFN weights: 2^-11 rel)
__global__ __launch_bounds__(256) void quantf16_kernel(
    const float* __restrict__ S, u16* __restrict__ H, int n)
{
  int i = blockIdx.x * 256 + threadIdx.x;
  const int stride = gridDim.x * 256;
  for (; i < n; i += stride) H[i] = f2h(S[i]);
}

// ---------------------------------------------------------------------------
// Equivariant projection: Y[n,o,c] = sum_i W[o,i] * X[n,i,c]  (layout [n][i*3+c])
// ---------------------------------------------------------------------------
__global__ __launch_bounds__(256) void proj_kernel(
    const float* __restrict__ X, const float* __restrict__ W, float* __restrict__ Y)
{
  __shared__ __align__(16) float xs[2][128][4];
  const int t = threadIdx.x;
  const int n0 = blockIdx.x * 2;
  for (int e = t; e < 768; e += 256) {
    int nl = (e >= 384);
    int r = e - nl * 384;
    xs[nl][r / 3][r % 3] = X[(size_t)(n0 + nl) * 384 + r];
  }
  __syncthreads();
  const int nl = t >> 7, o = t & 127;
  const float4* wrow = (const float4*)(W + o * 128);
  float a0 = 0.f, a1 = 0.f, a2 = 0.f;
#pragma unroll
  for (int j = 0; j < 32; ++j) {
    float4 wv = wrow[j];
    float w[4] = {wv.x, wv.y, wv.z, wv.w};
#pragma unroll
    for (int e = 0; e < 4; ++e) {
      float4 xv = *(const float4*)&xs[nl][j * 4 + e][0];
      a0 = fmaf(w[e], xv.x, a0);
      a1 = fmaf(w[e], xv.y, a1);
      a2 = fmaf(w[e], xv.z, a2);
    }
  }
  const size_t yb = (size_t)(n0 + nl) * 384 + o * 3;
  Y[yb + 0] = a0;
  Y[yb + 1] = a1;
  Y[yb + 2] = a2;
}

// ---------------------------------------------------------------------------
// Gathered multi-head attention, fp32.
// ---------------------------------------------------------------------------
__global__ __launch_bounds__(512) void attn_kernel(
    const float* __restrict__ Q, const float* __restrict__ K, const float* __restrict__ V,
    const int* __restrict__ IP, const int* __restrict__ KBC,
    const int* __restrict__ IPB, const int* __restrict__ FLAG, float* __restrict__ O)
{
  const int n = blockIdx.x;
  const int t = threadIdx.x;
  const int h = t >> 6, l = t & 63;
  __shared__ __align__(16) float qs[384];
  __shared__ float attn_s[8][64];
  __shared__ int gi_s[8][64];
  if (t < 96) ((float4*)qs)[t] = ((const float4*)(Q + (size_t)n * 384))[t];
  const int is64 = *FLAG;
  const long long* IP64 = (const long long*)IP;
  const long long* KBC64 = (const long long*)KBC;
  const long long* IPB64 = (const long long*)IPB;
  const int b = is64 ? (int)IPB64[n] : IPB[n];
  int ks0 = 0;
#pragma unroll
  for (int j = 0; j < 4; ++j) {
    int cnt = is64 ? (int)KBC64[j] : KBC[j];
    ks0 += (j < b) ? cnt : 0;  // exclusive cumsum
  }
  const int ip = is64 ? (int)IP64[(size_t)n * 64 + l] : IP[(size_t)n * 64 + l];
  const bool valid = ip >= 0;
  const int gi = ks0 + (valid ? ip : 0);
  __syncthreads();
  const float* kr = K + (size_t)gi * 384 + h * 48;
  float s = 0.f;
#pragma unroll
  for (int j = 0; j < 12; ++j) {
    float4 kv = ((const float4*)kr)[j];
    s = fmaf(kv.x, qs[h * 48 + j * 4 + 0], s);
    s = fmaf(kv.y, qs[h * 48 + j * 4 + 1], s);
    s = fmaf(kv.z, qs[h * 48 + j * 4 + 2], s);
    s = fmaf(kv.w, qs[h * 48 + j * 4 + 3], s);
  }
  s *= 0.25f;  // 1/sqrt(hd)
  if (!valid) s = -1e9f;
  float m = s;
  for (int off = 32; off; off >>= 1) m = fmaxf(m, __shfl_xor(m, off));
  float e = __expf(s - m);
  float sum = e;
  for (int off = 32; off; off >>= 1) sum += __shfl_xor(sum, off);
  attn_s[h][l] = e / sum;
  gi_s[h][l] = gi;
  __syncthreads();
  if (l < 48) {
    float acc = 0.f;
#pragma unroll 4
    for (int ll = 0; ll < 64; ++ll)
      acc = fmaf(attn_s[h][ll], V[(size_t)gi_s[h][ll] * 384 + h * 48 + l], acc);
    O[(size_t)n * 384 + h * 48 + l] = acc;
  }
}

// ---------------------------------------------------------------------------
// VN LayerNorm 1: h1 = VNLN(x + tgt2). Writes fp32 [(n*3+c)][128] (for ln2
// residual) AND an fp16 plane (FFN GEMM A-operand).
// ---------------------------------------------------------------------------
__global__ __launch_bounds__(128) void ln1_kernel(
    const float* __restrict__ X, const float* __restrict__ T2,
    const float* __restrict__ G, const float* __restrict__ Bb,
    float* __restrict__ Hf, u16* __restrict__ Hh)
{
  const int n = blockIdx.x, i = threadIdx.x;
  const size_t b0 = (size_t)n * 384 + i * 3;
  float v0 = X[b0 + 0] + T2[b0 + 0];
  float v1 = X[b0 + 1] + T2[b0 + 1];
  float v2 = X[b0 + 2] + T2[b0 + 2];
  float nn = sqrtf(v0 * v0 + v1 * v1 + v2 * v2 + 1e-6f);
  float s1 = nn, s2 = nn * nn;
  for (int off = 32; off; off >>= 1) { s1 += __shfl_xor(s1, off); s2 += __shfl_xor(s2, off); }
  __shared__ float red[4];
  if ((i & 63) == 0) { red[(i >> 6) * 2] = s1; red[(i >> 6) * 2 + 1] = s2; }
  __syncthreads();
  float mu = (red[0] + red[2]) * (1.0f / 128.0f);
  float ms = (red[1] + red[3]) * (1.0f / 128.0f);
  float var = ms - mu * mu;
  float nnew = (nn - mu) * rsqrtf(var + 1e-5f) * G[i] + Bb[i];
  float sc = nnew / nn;
  const size_t h0 = (size_t)n * 384 + i;  // [(n*3+c)][128]: n*384 + c*128 + i
  float o0 = v0 * sc, o1 = v1 * sc, o2 = v2 * sc;
  Hf[h0 + 0]   = o0;
  Hf[h0 + 128] = o1;
  Hf[h0 + 256] = o2;
  Hh[h0 + 0]   = f2h(o0);
  Hh[h0 + 128] = f2h(o1);
  Hh[h0 + 256] = f2h(o2);
}

// ---------------------------------------------------------------------------
// VN LayerNorm 2: out = VNLN(h1 + sum_z Gpart); fp32 in, fp32 out [n][i*3+c]
// ---------------------------------------------------------------------------
__global__ __launch_bounds__(128) void ln2_kernel(
    const float* __restrict__ Hf, const float* __restrict__ Gp,
    const float* __restrict__ G, const float* __restrict__ Bb, float* __restrict__ O)
{
  const int n = blockIdx.x, i = threadIdx.x;
  float v[3];
#pragma unroll
  for (int c = 0; c < 3; ++c) {
    float s = Hf[(size_t)n * 384 + c * 128 + i];
    const float* gp = Gp + (size_t)(n * 3 + c) * 128 + i;
#pragma unroll
    for (int z = 0; z < SPLITS; ++z) s += gp[(size_t)z * 6144 * 128];
    v[c] = s;
  }
  float nn = sqrtf(v[0] * v[0] + v[1] * v[1] + v[2] * v[2] + 1e-6f);
  float s1 = nn, s2 = nn * nn;
  for (int off = 32; off; off >>= 1) { s1 += __shfl_xor(s1, off); s2 += __shfl_xor(s2, off); }
  __shared__ float red[4];
  if ((i & 63) == 0) { red[(i >> 6) * 2] = s1; red[(i >> 6) * 2 + 1] = s2; }
  __syncthreads();
  float mu = (red[0] + red[2]) * (1.0f / 128.0f);
  float ms = (red[1] + red[3]) * (1.0f / 128.0f);
  float var = ms - mu * mu;
  float nnew = (nn - mu) * rsqrtf(var + 1e-5f) * G[i] + Bb[i];
  float sc = nnew / nn;
  const size_t o0 = (size_t)n * 384 + i * 3;
  O[o0 + 0] = v[0] * sc;
  O[o0 + 1] = v[1] * sc;
  O[o0 + 2] = v[2] * sc;
}

// ---------------------------------------------------------------------------
// VN-ReLU, vectorized x8, fp16, OUT-OF-PLACE (F,D -> P). No RMW anywhere.
// F/D/P layout: [(n*3+c)][o], stride DFF per c.
// ---------------------------------------------------------------------------
__global__ __launch_bounds__(256) void vnrelu8_kernel(
    const u16* __restrict__ F, const u16* __restrict__ D, u16* __restrict__ P)
{
  const size_t idx = (size_t)blockIdx.x * 256 + threadIdx.x;  // one per 8 elems
  const size_t n = idx >> 8;              // DFF/8 = 256 groups per token
  const size_t oo = (idx & 255) << 3;
  const size_t base = n * 3 * DFF + oo;
  s16x8 f0 = *(const s16x8*)(F + base);
  s16x8 f1 = *(const s16x8*)(F + base + DFF);
  s16x8 f2 = *(const s16x8*)(F + base + 2 * DFF);
  s16x8 d0 = *(const s16x8*)(D + base);
  s16x8 d1 = *(const s16x8*)(D + base + DFF);
  s16x8 d2 = *(const s16x8*)(D + base + 2 * DFF);
  s16x8 r0, r1, r2;
#pragma unroll
  for (int e = 0; e < 8; ++e) {
    float a0 = h2f((u16)f0[e]), a1 = h2f((u16)f1[e]), a2 = h2f((u16)f2[e]);
    float b0 = h2f((u16)d0[e]), b1 = h2f((u16)d1[e]), b2 = h2f((u16)d2[e]);
    float dot = a0 * b0 + a1 * b1 + a2 * b2;
    float r = (dot < 0.0f) ? dot / (b0 * b0 + b1 * b1 + b2 * b2 + 1e-6f) : 0.0f;
    r0[e] = (short)f2h(a0 - r * b0);
    r1[e] = (short)f2h(a1 - r * b1);
    r2[e] = (short)f2h(a2 - r * b2);
  }
  *(s16x8*)(P + base) = r0;
  *(s16x8*)(P + base + DFF) = r1;
  *(s16x8*)(P + base + 2 * DFF) = r2;
}

// ---------------------------------------------------------------------------
// fp16 NT GEMM, phase-scheduled 256x128 tile (T3+T4+T5, 2 blocks/CU).
// BK=32, 8 waves (2Mx4N), per-wave 128x32 out (acc 8x2 frags).
// LDS 3-buffer ring (73.7 KiB -> 2 blocks/CU co-resident), depth-2 gll16
// prefetch, 3 loads/wave/tile (2xA + 1xB).
// Per tile: 2 phases, each {ds_read subtile || issue gll16 -> barrier ->
// lgkmcnt(0) -> setprio(1) 8 MFMA setprio(0) -> barrier}.
// Boundary once per tile: counted vmcnt(3) (retires exactly tile t+1's 3
// own loads; never 0 mid-loop) + barrier publishes cross-wave.
// ---------------------------------------------------------------------------
__global__ __launch_bounds__(512, 4) void gemm_f16_256(
    const u16* __restrict__ A, const u16* __restrict__ B,
    u16* __restrict__ C, int M, int N, int K)
{
  __shared__ __align__(16) u16 lds[3][24][64][8];  // 73.7 KiB ring: 16 A + 8 B frags
  const int tid = threadIdx.x;
  const int wave = tid >> 6, lane = tid & 63;
  const int bm = blockIdx.x, bn = blockIdx.y;
  const int NT = K >> 5;
  const int fr = lane & 15;          // row within 16-row fragment
  const int kg = (lane >> 4) << 3;   // k sub-offset 0/8/16/24
  const int wm = wave >> 2, wn = wave & 3;   // 2 x 4 wave grid
  f32x4 acc[8][2] = {};

  auto stageA = [&](int buf, int kt) {   // 2 gll16: A-frags {2w, 2w+1} (0..15)
#pragma unroll
    for (int i = 0; i < 2; ++i) {
      const int f = wave * 2 + i;
      gll16(A + (size_t)(bm * 256 + f * 16 + fr) * K + (kt << 5) + kg,
            &lds[buf][f][0][0]);
    }
  };
  auto stageB = [&](int buf, int kt) {   // 1 gll16: B-frag {w} (slots 16..23)
    gll16(B + (size_t)(bn * 128 + wave * 16 + fr) * K + (kt << 5) + kg,
          &lds[buf][16 + wave][0][0]);
  };

  // prologue: tiles 0,1 in flight (6 loads/wave); retire tile 0, publish.
  stageA(0, 0); stageB(0, 0);
  stageA(1, 1); stageB(1, 1);
  asm volatile("s_waitcnt vmcnt(3)" ::: "memory");
  __builtin_amdgcn_s_barrier();
  __builtin_amdgcn_sched_barrier(0);

  s16x8 bf[2];
  for (int t = 0; t < NT; ++t) {
    const int cur = t % 3;
    const int nx2 = (t + 2) % 3;
    // ---- phase 0: a-half 0 + all b ----
    s16x8 af[4];
#pragma unroll
    for (int i = 0; i < 4; ++i)
      af[i] = *(const s16x8*)(&lds[cur][wm * 8 + i][lane][0]);
#pragma unroll
    for (int j = 0; j < 2; ++j)
      bf[j] = *(const s16x8*)(&lds[cur][16 + wn * 2 + j][lane][0]);
    if (t + 2 < NT) stageA(nx2, t + 2);
    __builtin_amdgcn_s_barrier();
    asm volatile("s_waitcnt lgkmcnt(0)" ::: "memory");
    __builtin_amdgcn_sched_barrier(0);
    __builtin_amdgcn_s_setprio(1);
#pragma unroll
    for (int i = 0; i < 4; ++i)
#pragma unroll
      for (int j = 0; j < 2; ++j) mfma16h(acc[i][j], af[i], bf[j]);
    __builtin_amdgcn_s_setprio(0);
    __builtin_amdgcn_s_barrier();
    // ---- phase 1: a-half 1, b reused from registers ----
#pragma unroll
    for (int i = 0; i < 4; ++i)
      af[i] = *(const s16x8*)(&lds[cur][wm * 8 + 4 + i][lane][0]);
    if (t + 2 < NT) stageB(nx2, t + 2);
    __builtin_amdgcn_s_barrier();
    asm volatile("s_waitcnt lgkmcnt(0)" ::: "memory");
    __builtin_amdgcn_sched_barrier(0);
    __builtin_amdgcn_s_setprio(1);
#pragma unroll
    for (int i = 0; i < 4; ++i)
#pragma unroll
      for (int j = 0; j < 2; ++j) mfma16h(acc[4 + i][j], af[i], bf[j]);
    __builtin_amdgcn_s_setprio(0);
    __builtin_amdgcn_s_barrier();
    // ---- tile boundary: tile t+1 must be fully landed & published ----
    if (t + 1 < NT) {
      if (t + 2 < NT) {
        asm volatile("s_waitcnt vmcnt(3)" ::: "memory");  // retire t+1's 3, keep t+2's
      } else {
        asm volatile("s_waitcnt vmcnt(0)" ::: "memory");  // tail: nothing newer
      }
      __builtin_amdgcn_s_barrier();
      __builtin_amdgcn_sched_barrier(0);
    }
  }

  // epilogue: C/D frag layout col = lane&15, row = (lane>>4)*4 + reg
  const int r0 = bm * 256 + wm * 128 + (lane >> 4) * 4;
  const int c0 = bn * 128 + wn * 32 + (lane & 15);
#pragma unroll
  for (int ia = 0; ia < 8; ++ia)
#pragma unroll
    for (int jb = 0; jb < 2; ++jb)
#pragma unroll
      for (int r = 0; r < 4; ++r)
        C[(size_t)(r0 + ia * 16 + r) * N + (c0 + jb * 16)] = f2h(acc[ia][jb][r]);
}

// ---------------------------------------------------------------------------
// fp16 NT GEMM: 128x128 tile, BK=32, 4 waves. Register-staged LDS, 2 barriers
// per K-step (replay-proven dynamics). Used for W1 / W2 (small-K shapes).
// MODE 0: fp16 C. MODE 1: fp32 partials at (float*)C + bz*M*N (split-K on z).
// ---------------------------------------------------------------------------
template <int MODE>
__global__ __launch_bounds__(256) void gemm_f16(
    const u16* __restrict__ A, const u16* __restrict__ B,
    void* __restrict__ Cout, int M, int N, int K)
{
  __shared__ __align__(16) u16 lds[2][8][64][8];  // 16 KiB: A,B
  const int tid = threadIdx.x;
  const int wave = tid >> 6, lane = tid & 63;
  const int bm = blockIdx.x, bn = blockIdx.y, bz = blockIdx.z;
  const int kChunk = K / (int)gridDim.z;
  const int k0 = bz * kChunk;
  const int nt = kChunk >> 5;
  const int fr = lane & 15;
  const int kg = (lane >> 4) << 3;
  f32x4 acc[4][4] = {};
  const int wr = wave >> 1, wc = wave & 1;

  s16x8 ra[2], rb[2];
  auto load_regs = [&](int kt) {
    const int kk = k0 + (kt << 5) + kg;
#pragma unroll
    for (int i = 0; i < 2; ++i) {
      const int f = i * 4 + wave;
      ra[i] = *(const s16x8*)(A + (size_t)(bm * 128 + f * 16 + fr) * K + kk);
      rb[i] = *(const s16x8*)(B + (size_t)(bn * 128 + f * 16 + fr) * K + kk);
    }
  };
  auto write_lds = [&]() {
#pragma unroll
    for (int i = 0; i < 2; ++i) {
      const int f = i * 4 + wave;
      *(s16x8*)(&lds[0][f][lane][0]) = ra[i];
      *(s16x8*)(&lds[1][f][lane][0]) = rb[i];
    }
  };
  auto compute = [&]() {
    s16x8 af[4], bf[4];
#pragma unroll
    for (int m = 0; m < 4; ++m) af[m] = *(const s16x8*)(&lds[0][wr * 4 + m][lane][0]);
#pragma unroll
    for (int n2 = 0; n2 < 4; ++n2) bf[n2] = *(const s16x8*)(&lds[1][wc * 4 + n2][lane][0]);
#pragma unroll
    for (int m = 0; m < 4; ++m)
#pragma unroll
      for (int n2 = 0; n2 < 4; ++n2) mfma16h(acc[m][n2], af[m], bf[n2]);
  };

  load_regs(0);
  write_lds();
  for (int t = 0; t < nt; ++t) {
    __syncthreads();
    if (t + 1 < nt) load_regs(t + 1);
    compute();
    __syncthreads();
    if (t + 1 < nt) write_lds();
  }

  const int r0 = bm * 128 + wr * 64 + (lane >> 4) * 4;
  const int c0 = bn * 128 + wc * 64 + (lane & 15);
  if constexpr (MODE == 0) {
    u16* C = (u16*)Cout;
#pragma unroll
    for (int m = 0; m < 4; ++m)
#pragma unroll
      for (int n2 = 0; n2 < 4; ++n2)
#pragma unroll
        for (int r = 0; r < 4; ++r)
          C[(size_t)(r0 + m * 16 + r) * N + (c0 + n2 * 16)] = f2h(acc[m][n2][r]);
  } else {
    float* C = (float*)Cout + (size_t)bz * M * N;
#pragma unroll
    for (int m = 0; m < 4; ++m)
#pragma unroll
      for (int n2 = 0; n2 < 4; ++n2)
#pragma unroll
        for (int r = 0; r < 4; ++r)
          C[(size_t)(r0 + m * 16 + r) * N + (c0 + n2 * 16)] = acc[m][n2][r];
  }
}

// ---------------------------------------------------------------------------
extern "C" void kernel_launch(void* const* d_in, const int* in_sizes, int n_in,
                              void* d_out, int out_size, void* d_ws, size_t ws_size,
                              hipStream_t stream)
{
  const float* tgt  = (const float*)d_in[0];
  const float* mem  = (const float*)d_in[1];
  const float* Wq   = (const float*)d_in[2];
  const float* Wk   = (const float*)d_in[3];
  const float* Wv   = (const float*)d_in[4];
  const float* Wo   = (const float*)d_in[5];
  const float* ln1g = (const float*)d_in[6];
  const float* ln1b = (const float*)d_in[7];
  const float* ln2g = (const float*)d_in[8];
  const float* ln2b = (const float*)d_in[9];
  const float* W1   = (const float*)d_in[10];
  const float* Wd   = (const float*)d_in[11];
  const float* W2   = (const float*)d_in[12];
  const int* ipair  = (const int*)d_in[13];
  const int* kbc    = (const int*)d_in[15];
  const int* ipb    = (const int*)d_in[16];
  float* out = (float*)d_out;

  char* p = (char*)d_ws;
  auto alloc = [&](size_t bytes) {
    char* r = p;
    p += (bytes + 255) & ~(size_t)255;
    return (void*)r;
  };
  float* q    = (float*)alloc((size_t)NQ * 384 * 4);
  float* kbuf = (float*)alloc((size_t)NK * 384 * 4);
  float* vbuf = (float*)alloc((size_t)NK * 384 * 4);
  float* aout = (float*)alloc((size_t)NQ * 384 * 4);
  float* tgt2 = (float*)alloc((size_t)NQ * 384 * 4);
  float* h1f  = (float*)alloc((size_t)NQ * 384 * 4);   // [(n*3+c)][128] fp32
  u16* h1h  = (u16*)alloc((size_t)6144 * 128 * 2);     // fp16 plane
  u16* W1h  = (u16*)alloc((size_t)DFF * 128 * 2);      // fp16
  u16* Wdh  = (u16*)alloc((size_t)DFF * DFF * 2);      // fp16
  u16* W2h  = (u16*)alloc((size_t)128 * DFF * 2);      // fp16
  u16* Ff16 = (u16*)alloc((size_t)6144 * DFF * 2);     // [(n*3+c)][dff] fp16 (W1 out)
  u16* Dm   = (u16*)alloc((size_t)6144 * DFF * 2);     // fp16 (Wd out)
  u16* Fp   = (u16*)alloc((size_t)6144 * DFF * 2);     // fp16 (vnrelu out)
  float* Gp = (float*)Ff16;  // alias: Ff16 (25.2 MB) dead after vnrelu reads it;
                             // W2-gemm reads Fp and writes Gp — no overlap.
  int* dflag = (int*)alloc(256);

  detect_i64_kernel<<<1, 64, 0, stream>>>(ipair, dflag);
  quantf16_kernel<<<256, 256, 0, stream>>>(W1, W1h, DFF * 128);
  quantf16_kernel<<<2048, 256, 0, stream>>>(Wd, Wdh, DFF * DFF);
  quantf16_kernel<<<256, 256, 0, stream>>>(W2, W2h, 128 * DFF);

  proj_kernel<<<NQ / 2, 256, 0, stream>>>(tgt, Wq, q);
  proj_kernel<<<NK / 2, 256, 0, stream>>>(mem, Wk, kbuf);
  proj_kernel<<<NK / 2, 256, 0, stream>>>(mem, Wv, vbuf);
  attn_kernel<<<NQ, 512, 0, stream>>>(q, kbuf, vbuf, ipair, kbc, ipb, dflag, aout);
  proj_kernel<<<NQ / 2, 256, 0, stream>>>(aout, Wo, tgt2);
  ln1_kernel<<<NQ, 128, 0, stream>>>(tgt, tgt2, ln1g, ln1b, h1f, h1h);

  // F = h1 * W1^T   (M=6144, N=2048, K=128), fp16, 128^2 structure
  gemm_f16<0><<<dim3(48, 16, 1), 256, 0, stream>>>(h1h, W1h, Ff16, 6144, DFF, 128);
  // D = F * Wd^T    (M=6144, N=2048, K=2048), fp16, 256x128 phase-scheduled
  gemm_f16_256<<<dim3(24, 16, 1), 512, 0, stream>>>(Ff16, Wdh, Dm, 6144, DFF, DFF);
  // F' = vnrelu(F, D) -> Fp, out-of-place, x8 vectorized
  vnrelu8_kernel<<<(NQ * DFF) / (256 * 8), 256, 0, stream>>>(Ff16, Dm, Fp);
  // Gp partials = F' * W2^T  (M=6144, N=128, K=2048), split-K=8, fp32 partials
  gemm_f16<1><<<dim3(48, 1, SPLITS), 256, 0, stream>>>(Fp, W2h, Gp, 6144, 128, DFF);
  ln2_kernel<<<NQ, 128, 0, stream>>>(h1f, Gp, ln2g, ln2b, out);
}

// Round 13
// 257.334 us; speedup vs baseline: 1.1518x; 1.1518x over previous
//
#include <hip/hip_runtime.h>
#include <stdint.h>

// Problem constants (fixed by the reference)
#define NQ 2048
#define NK 4096
#define DFF 2048
#define SPLITS 8

using u16 = unsigned short;
typedef float f32x4 __attribute__((ext_vector_type(4)));
typedef short s16x8 __attribute__((ext_vector_type(8)));
typedef __attribute__((address_space(3))) void as3_void;
typedef __attribute__((address_space(1))) void as1_void;

__device__ __forceinline__ u16 f2h(float f) {           // fp32 -> fp16 bits (RNE)
  _Float16 h = (_Float16)f;
  return __builtin_bit_cast(u16, h);
}
__device__ __forceinline__ float h2f(u16 u) {
  return (float)__builtin_bit_cast(_Float16, u);
}
__device__ __forceinline__ void mfma16h(f32x4& d, s16x8 a, s16x8 b) {  // fp16
  asm volatile("v_mfma_f32_16x16x32_f16 %0, %1, %2, %0" : "+v"(d) : "v"(a), "v"(b));
}
// async global->LDS DMA, 16B/lane; LDS dest = wave-uniform base + lane*16.
__device__ __forceinline__ void gll16(const void* g, const void* l) {
  uint32_t off = (uint32_t)(uintptr_t)l;
  off = (uint32_t)__builtin_amdgcn_readfirstlane((int)off);
  __builtin_amdgcn_global_load_lds((const as1_void*)(uintptr_t)g,
                                   (as3_void*)(uintptr_t)off, 16, 0, 0);
}

// ---------------------------------------------------------------------------
// int64-vs-int32 detector for index inputs.
// ---------------------------------------------------------------------------
__global__ void detect_i64_kernel(const int* __restrict__ IP, int* __restrict__ flag) {
  if (threadIdx.x == 0 && blockIdx.x == 0) {
    int f = 1;
    for (int j = 1; j < 128; j += 2) f &= (IP[j] == 0);
    *flag = f;
  }
}

// fp32 -> fp16 single-plane quantizer (FFN weights: 2^-11 rel)
__global__ __launch_bounds__(256) void quantf16_kernel(
    const float* __restrict__ S, u16* __restrict__ H, int n)
{
  int i = blockIdx.x * 256 + threadIdx.x;
  const int stride = gridDim.x * 256;
  for (; i < n; i += stride) H[i] = f2h(S[i]);
}

// ---------------------------------------------------------------------------
// Equivariant projection: Y[n,o,c] = sum_i W[o,i] * X[n,i,c]  (layout [n][i*3+c])
// Optional fp16 side-output Yh (same layout) for attention K/V gather.
// ---------------------------------------------------------------------------
__global__ __launch_bounds__(256) void proj_kernel(
    const float* __restrict__ X, const float* __restrict__ W,
    float* __restrict__ Y, u16* __restrict__ Yh)
{
  __shared__ __align__(16) float xs[2][128][4];
  const int t = threadIdx.x;
  const int n0 = blockIdx.x * 2;
  for (int e = t; e < 768; e += 256) {
    int nl = (e >= 384);
    int r = e - nl * 384;
    xs[nl][r / 3][r % 3] = X[(size_t)(n0 + nl) * 384 + r];
  }
  __syncthreads();
  const int nl = t >> 7, o = t & 127;
  const float4* wrow = (const float4*)(W + o * 128);
  float a0 = 0.f, a1 = 0.f, a2 = 0.f;
#pragma unroll
  for (int j = 0; j < 32; ++j) {
    float4 wv = wrow[j];
    float w[4] = {wv.x, wv.y, wv.z, wv.w};
#pragma unroll
    for (int e = 0; e < 4; ++e) {
      float4 xv = *(const float4*)&xs[nl][j * 4 + e][0];
      a0 = fmaf(w[e], xv.x, a0);
      a1 = fmaf(w[e], xv.y, a1);
      a2 = fmaf(w[e], xv.z, a2);
    }
  }
  const size_t yb = (size_t)(n0 + nl) * 384 + o * 3;
  Y[yb + 0] = a0;
  Y[yb + 1] = a1;
  Y[yb + 2] = a2;
  if (Yh) {
    Yh[yb + 0] = f2h(a0);
    Yh[yb + 1] = f2h(a1);
    Yh[yb + 2] = f2h(a2);
  }
}

// ---------------------------------------------------------------------------
// Gathered multi-head attention. Q fp32 (LDS-staged); K/V fp16 (halved gather
// bytes + load counts; scores/PV accumulate fp32).
// ---------------------------------------------------------------------------
__global__ __launch_bounds__(512) void attn_kernel(
    const float* __restrict__ Q, const u16* __restrict__ K, const u16* __restrict__ V,
    const int* __restrict__ IP, const int* __restrict__ KBC,
    const int* __restrict__ IPB, const int* __restrict__ FLAG, float* __restrict__ O)
{
  const int n = blockIdx.x;
  const int t = threadIdx.x;
  const int h = t >> 6, l = t & 63;
  __shared__ __align__(16) float qs[384];
  __shared__ float attn_s[8][64];
  __shared__ int gi_s[8][64];
  if (t < 96) ((float4*)qs)[t] = ((const float4*)(Q + (size_t)n * 384))[t];
  const int is64 = *FLAG;
  const long long* IP64 = (const long long*)IP;
  const long long* KBC64 = (const long long*)KBC;
  const long long* IPB64 = (const long long*)IPB;
  const int b = is64 ? (int)IPB64[n] : IPB[n];
  int ks0 = 0;
#pragma unroll
  for (int j = 0; j < 4; ++j) {
    int cnt = is64 ? (int)KBC64[j] : KBC[j];
    ks0 += (j < b) ? cnt : 0;  // exclusive cumsum
  }
  const int ip = is64 ? (int)IP64[(size_t)n * 64 + l] : IP[(size_t)n * 64 + l];
  const bool valid = ip >= 0;
  const int gi = ks0 + (valid ? ip : 0);
  __syncthreads();
  const u16* kr = K + (size_t)gi * 384 + h * 48;
  float s = 0.f;
#pragma unroll
  for (int j = 0; j < 6; ++j) {
    s16x8 kv = *(const s16x8*)(kr + j * 8);
#pragma unroll
    for (int e = 0; e < 8; ++e) s = fmaf(h2f((u16)kv[e]), qs[h * 48 + j * 8 + e], s);
  }
  s *= 0.25f;  // 1/sqrt(hd)
  if (!valid) s = -1e9f;
  float m = s;
  for (int off = 32; off; off >>= 1) m = fmaxf(m, __shfl_xor(m, off));
  float e = __expf(s - m);
  float sum = e;
  for (int off = 32; off; off >>= 1) sum += __shfl_xor(sum, off);
  attn_s[h][l] = e / sum;
  gi_s[h][l] = gi;
  __syncthreads();
  if (l < 48) {
    float acc = 0.f;
#pragma unroll 4
    for (int ll = 0; ll < 64; ++ll)
      acc = fmaf(attn_s[h][ll], h2f(V[(size_t)gi_s[h][ll] * 384 + h * 48 + l]), acc);
    O[(size_t)n * 384 + h * 48 + l] = acc;
  }
}

// ---------------------------------------------------------------------------
// VN LayerNorm 1: h1 = VNLN(x + tgt2). Writes fp32 [(n*3+c)][128] (for ln2
// residual) AND an fp16 plane (FFN GEMM A-operand).
// ---------------------------------------------------------------------------
__global__ __launch_bounds__(128) void ln1_kernel(
    const float* __restrict__ X, const float* __restrict__ T2,
    const float* __restrict__ G, const float* __restrict__ Bb,
    float* __restrict__ Hf, u16* __restrict__ Hh)
{
  const int n = blockIdx.x, i = threadIdx.x;
  const size_t b0 = (size_t)n * 384 + i * 3;
  float v0 = X[b0 + 0] + T2[b0 + 0];
  float v1 = X[b0 + 1] + T2[b0 + 1];
  float v2 = X[b0 + 2] + T2[b0 + 2];
  float nn = sqrtf(v0 * v0 + v1 * v1 + v2 * v2 + 1e-6f);
  float s1 = nn, s2 = nn * nn;
  for (int off = 32; off; off >>= 1) { s1 += __shfl_xor(s1, off); s2 += __shfl_xor(s2, off); }
  __shared__ float red[4];
  if ((i & 63) == 0) { red[(i >> 6) * 2] = s1; red[(i >> 6) * 2 + 1] = s2; }
  __syncthreads();
  float mu = (red[0] + red[2]) * (1.0f / 128.0f);
  float ms = (red[1] + red[3]) * (1.0f / 128.0f);
  float var = ms - mu * mu;
  float nnew = (nn - mu) * rsqrtf(var + 1e-5f) * G[i] + Bb[i];
  float sc = nnew / nn;
  const size_t h0 = (size_t)n * 384 + i;  // [(n*3+c)][128]: n*384 + c*128 + i
  float o0 = v0 * sc, o1 = v1 * sc, o2 = v2 * sc;
  Hf[h0 + 0]   = o0;
  Hf[h0 + 128] = o1;
  Hf[h0 + 256] = o2;
  Hh[h0 + 0]   = f2h(o0);
  Hh[h0 + 128] = f2h(o1);
  Hh[h0 + 256] = f2h(o2);
}

// ---------------------------------------------------------------------------
// VN LayerNorm 2: out = VNLN(h1 + sum_z Gpart); fp32 in, fp32 out [n][i*3+c]
// ---------------------------------------------------------------------------
__global__ __launch_bounds__(128) void ln2_kernel(
    const float* __restrict__ Hf, const float* __restrict__ Gp,
    const float* __restrict__ G, const float* __restrict__ Bb, float* __restrict__ O)
{
  const int n = blockIdx.x, i = threadIdx.x;
  float v[3];
#pragma unroll
  for (int c = 0; c < 3; ++c) {
    float s = Hf[(size_t)n * 384 + c * 128 + i];
    const float* gp = Gp + (size_t)(n * 3 + c) * 128 + i;
#pragma unroll
    for (int z = 0; z < SPLITS; ++z) s += gp[(size_t)z * 6144 * 128];
    v[c] = s;
  }
  float nn = sqrtf(v[0] * v[0] + v[1] * v[1] + v[2] * v[2] + 1e-6f);
  float s1 = nn, s2 = nn * nn;
  for (int off = 32; off; off >>= 1) { s1 += __shfl_xor(s1, off); s2 += __shfl_xor(s2, off); }
  __shared__ float red[4];
  if ((i & 63) == 0) { red[(i >> 6) * 2] = s1; red[(i >> 6) * 2 + 1] = s2; }
  __syncthreads();
  float mu = (red[0] + red[2]) * (1.0f / 128.0f);
  float ms = (red[1] + red[3]) * (1.0f / 128.0f);
  float var = ms - mu * mu;
  float nnew = (nn - mu) * rsqrtf(var + 1e-5f) * G[i] + Bb[i];
  float sc = nnew / nn;
  const size_t o0 = (size_t)n * 384 + i * 3;
  O[o0 + 0] = v[0] * sc;
  O[o0 + 1] = v[1] * sc;
  O[o0 + 2] = v[2] * sc;
}

// ---------------------------------------------------------------------------
// VN-ReLU, vectorized x8, fp16, OUT-OF-PLACE (F,D -> P). No RMW anywhere.
// F/D/P layout: [(n*3+c)][o], stride DFF per c.
// ---------------------------------------------------------------------------
__global__ __launch_bounds__(256) void vnrelu8_kernel(
    const u16* __restrict__ F, const u16* __restrict__ D, u16* __restrict__ P)
{
  const size_t idx = (size_t)blockIdx.x * 256 + threadIdx.x;  // one per 8 elems
  const size_t n = idx >> 8;              // DFF/8 = 256 groups per token
  const size_t oo = (idx & 255) << 3;
  const size_t base = n * 3 * DFF + oo;
  s16x8 f0 = *(const s16x8*)(F + base);
  s16x8 f1 = *(const s16x8*)(F + base + DFF);
  s16x8 f2 = *(const s16x8*)(F + base + 2 * DFF);
  s16x8 d0 = *(const s16x8*)(D + base);
  s16x8 d1 = *(const s16x8*)(D + base + DFF);
  s16x8 d2 = *(const s16x8*)(D + base + 2 * DFF);
  s16x8 r0, r1, r2;
#pragma unroll
  for (int e = 0; e < 8; ++e) {
    float a0 = h2f((u16)f0[e]), a1 = h2f((u16)f1[e]), a2 = h2f((u16)f2[e]);
    float b0 = h2f((u16)d0[e]), b1 = h2f((u16)d1[e]), b2 = h2f((u16)d2[e]);
    float dot = a0 * b0 + a1 * b1 + a2 * b2;
    float r = (dot < 0.0f) ? dot / (b0 * b0 + b1 * b1 + b2 * b2 + 1e-6f) : 0.0f;
    r0[e] = (short)f2h(a0 - r * b0);
    r1[e] = (short)f2h(a1 - r * b1);
    r2[e] = (short)f2h(a2 - r * b2);
  }
  *(s16x8*)(P + base) = r0;
  *(s16x8*)(P + base + DFF) = r1;
  *(s16x8*)(P + base + 2 * DFF) = r2;
}

// ---------------------------------------------------------------------------
// fp16 NT GEMM, phase-scheduled 256x256 tile (R11-proven best: 74 us).
// BK=32, 8 waves (2Mx4N), per-wave 128x64 out (acc 8x4 frags).
// LDS 3-buffer ring (96 KiB), depth-2 gll16 prefetch.
// Per tile: 2 phases, each {ds_read subtile || issue 2 gll16 -> barrier ->
// lgkmcnt(0) -> setprio(1) 16 MFMA setprio(0) -> barrier}.
// Boundary once per tile: counted vmcnt(4) (never 0 mid-loop) + barrier.
// ---------------------------------------------------------------------------
__global__ __launch_bounds__(512, 1) void gemm_f16_256(
    const u16* __restrict__ A, const u16* __restrict__ B,
    u16* __restrict__ C, int M, int N, int K)
{
  __shared__ __align__(16) u16 lds[3][2][16][64][8];  // 96 KiB ring
  const int tid = threadIdx.x;
  const int wave = tid >> 6, lane = tid & 63;
  const int bm = blockIdx.x, bn = blockIdx.y;
  const int NT = K >> 5;
  const int fr = lane & 15;          // row within 16-row fragment
  const int kg = (lane >> 4) << 3;   // k sub-offset 0/8/16/24
  const int wm = wave >> 2, wn = wave & 3;   // 2 x 4 wave grid
  f32x4 acc[8][4] = {};

  auto stageA = [&](int buf, int kt) {   // 2 gll16: A-frags {2w, 2w+1}
#pragma unroll
    for (int i = 0; i < 2; ++i) {
      const int f = wave * 2 + i;
      gll16(A + (size_t)(bm * 256 + f * 16 + fr) * K + (kt << 5) + kg,
            &lds[buf][0][f][0][0]);
    }
  };
  auto stageB = [&](int buf, int kt) {   // 2 gll16: B-frags {2w, 2w+1}
#pragma unroll
    for (int i = 0; i < 2; ++i) {
      const int f = wave * 2 + i;
      gll16(B + (size_t)(bn * 256 + f * 16 + fr) * K + (kt << 5) + kg,
            &lds[buf][1][f][0][0]);
    }
  };

  // prologue: tiles 0,1 in flight (8 loads/wave); retire tile 0, publish.
  stageA(0, 0); stageB(0, 0);
  stageA(1, 1); stageB(1, 1);
  asm volatile("s_waitcnt vmcnt(4)" ::: "memory");
  __builtin_amdgcn_s_barrier();
  __builtin_amdgcn_sched_barrier(0);

  s16x8 bf[4];
  for (int t = 0; t < NT; ++t) {
    const int cur = t % 3;
    const int nx2 = (t + 2) % 3;
    // ---- phase 0: a-half 0 + all b ----
    s16x8 af[4];
#pragma unroll
    for (int i = 0; i < 4; ++i)
      af[i] = *(const s16x8*)(&lds[cur][0][wm * 8 + i][lane][0]);
#pragma unroll
    for (int j = 0; j < 4; ++j)
      bf[j] = *(const s16x8*)(&lds[cur][1][wn * 4 + j][lane][0]);
    if (t + 2 < NT) stageA(nx2, t + 2);
    __builtin_amdgcn_s_barrier();
    asm volatile("s_waitcnt lgkmcnt(0)" ::: "memory");
    __builtin_amdgcn_sched_barrier(0);
    __builtin_amdgcn_s_setprio(1);
#pragma unroll
    for (int i = 0; i < 4; ++i)
#pragma unroll
      for (int j = 0; j < 4; ++j) mfma16h(acc[i][j], af[i], bf[j]);
    __builtin_amdgcn_s_setprio(0);
    __builtin_amdgcn_s_barrier();
    // ---- phase 1: a-half 1, b reused from registers ----
#pragma unroll
    for (int i = 0; i < 4; ++i)
      af[i] = *(const s16x8*)(&lds[cur][0][wm * 8 + 4 + i][lane][0]);
    if (t + 2 < NT) stageB(nx2, t + 2);
    __builtin_amdgcn_s_barrier();
    asm volatile("s_waitcnt lgkmcnt(0)" ::: "memory");
    __builtin_amdgcn_sched_barrier(0);
    __builtin_amdgcn_s_setprio(1);
#pragma unroll
    for (int i = 0; i < 4; ++i)
#pragma unroll
      for (int j = 0; j < 4; ++j) mfma16h(acc[4 + i][j], af[i], bf[j]);
    __builtin_amdgcn_s_setprio(0);
    __builtin_amdgcn_s_barrier();
    // ---- tile boundary: tile t+1 must be fully landed & published ----
    if (t + 1 < NT) {
      if (t + 2 < NT) {
        asm volatile("s_waitcnt vmcnt(4)" ::: "memory");  // retire t+1's 4, keep t+2's
      } else {
        asm volatile("s_waitcnt vmcnt(0)" ::: "memory");  // tail: nothing newer
      }
      __builtin_amdgcn_s_barrier();
      __builtin_amdgcn_sched_barrier(0);
    }
  }

  // epilogue: C/D frag layout col = lane&15, row = (lane>>4)*4 + reg
  const int r0 = bm * 256 + wm * 128 + (lane >> 4) * 4;
  const int c0 = bn * 256 + wn * 64 + (lane & 15);
#pragma unroll
  for (int ia = 0; ia < 8; ++ia)
#pragma unroll
    for (int jb = 0; jb < 4; ++jb)
#pragma unroll
      for (int r = 0; r < 4; ++r)
        C[(size_t)(r0 + ia * 16 + r) * N + (c0 + jb * 16)] = f2h(acc[ia][jb][r]);
}

// ---------------------------------------------------------------------------
// fp16 NT GEMM: 128x128 tile, BK=32, 4 waves. Register-staged LDS, 2 barriers
// per K-step (replay-proven dynamics). Used for W1 / W2 (small-K shapes).
// MODE 0: fp16 C. MODE 1: fp32 partials at (float*)C + bz*M*N (split-K on z).
// ---------------------------------------------------------------------------
template <int MODE>
__global__ __launch_bounds__(256) void gemm_f16(
    const u16* __restrict__ A, const u16* __restrict__ B,
    void* __restrict__ Cout, int M, int N, int K)
{
  __shared__ __align__(16) u16 lds[2][8][64][8];  // 16 KiB: A,B
  const int tid = threadIdx.x;
  const int wave = tid >> 6, lane = tid & 63;
  const int bm = blockIdx.x, bn = blockIdx.y, bz = blockIdx.z;
  const int kChunk = K / (int)gridDim.z;
  const int k0 = bz * kChunk;
  const int nt = kChunk >> 5;
  const int fr = lane & 15;
  const int kg = (lane >> 4) << 3;
  f32x4 acc[4][4] = {};
  const int wr = wave >> 1, wc = wave & 1;

  s16x8 ra[2], rb[2];
  auto load_regs = [&](int kt) {
    const int kk = k0 + (kt << 5) + kg;
#pragma unroll
    for (int i = 0; i < 2; ++i) {
      const int f = i * 4 + wave;
      ra[i] = *(const s16x8*)(A + (size_t)(bm * 128 + f * 16 + fr) * K + kk);
      rb[i] = *(const s16x8*)(B + (size_t)(bn * 128 + f * 16 + fr) * K + kk);
    }
  };
  auto write_lds = [&]() {
#pragma unroll
    for (int i = 0; i < 2; ++i) {
      const int f = i * 4 + wave;
      *(s16x8*)(&lds[0][f][lane][0]) = ra[i];
      *(s16x8*)(&lds[1][f][lane][0]) = rb[i];
    }
  };
  auto compute = [&]() {
    s16x8 af[4], bf[4];
#pragma unroll
    for (int m = 0; m < 4; ++m) af[m] = *(const s16x8*)(&lds[0][wr * 4 + m][lane][0]);
#pragma unroll
    for (int n2 = 0; n2 < 4; ++n2) bf[n2] = *(const s16x8*)(&lds[1][wc * 4 + n2][lane][0]);
#pragma unroll
    for (int m = 0; m < 4; ++m)
#pragma unroll
      for (int n2 = 0; n2 < 4; ++n2) mfma16h(acc[m][n2], af[m], bf[n2]);
  };

  load_regs(0);
  write_lds();
  for (int t = 0; t < nt; ++t) {
    __syncthreads();
    if (t + 1 < nt) load_regs(t + 1);
    compute();
    __syncthreads();
    if (t + 1 < nt) write_lds();
  }

  const int r0 = bm * 128 + wr * 64 + (lane >> 4) * 4;
  const int c0 = bn * 128 + wc * 64 + (lane & 15);
  if constexpr (MODE == 0) {
    u16* C = (u16*)Cout;
#pragma unroll
    for (int m = 0; m < 4; ++m)
#pragma unroll
      for (int n2 = 0; n2 < 4; ++n2)
#pragma unroll
        for (int r = 0; r < 4; ++r)
          C[(size_t)(r0 + m * 16 + r) * N + (c0 + n2 * 16)] = f2h(acc[m][n2][r]);
  } else {
    float* C = (float*)Cout + (size_t)bz * M * N;
#pragma unroll
    for (int m = 0; m < 4; ++m)
#pragma unroll
      for (int n2 = 0; n2 < 4; ++n2)
#pragma unroll
        for (int r = 0; r < 4; ++r)
          C[(size_t)(r0 + m * 16 + r) * N + (c0 + n2 * 16)] = acc[m][n2][r];
  }
}

// ---------------------------------------------------------------------------
extern "C" void kernel_launch(void* const* d_in, const int* in_sizes, int n_in,
                              void* d_out, int out_size, void* d_ws, size_t ws_size,
                              hipStream_t stream)
{
  const float* tgt  = (const float*)d_in[0];
  const float* mem  = (const float*)d_in[1];
  const float* Wq   = (const float*)d_in[2];
  const float* Wk   = (const float*)d_in[3];
  const float* Wv   = (const float*)d_in[4];
  const float* Wo   = (const float*)d_in[5];
  const float* ln1g = (const float*)d_in[6];
  const float* ln1b = (const float*)d_in[7];
  const float* ln2g = (const float*)d_in[8];
  const float* ln2b = (const float*)d_in[9];
  const float* W1   = (const float*)d_in[10];
  const float* Wd   = (const float*)d_in[11];
  const float* W2   = (const float*)d_in[12];
  const int* ipair  = (const int*)d_in[13];
  const int* kbc    = (const int*)d_in[15];
  const int* ipb    = (const int*)d_in[16];
  float* out = (float*)d_out;

  char* p = (char*)d_ws;
  auto alloc = [&](size_t bytes) {
    char* r = p;
    p += (bytes + 255) & ~(size_t)255;
    return (void*)r;
  };
  float* q    = (float*)alloc((size_t)NQ * 384 * 4);
  float* kbuf = (float*)alloc((size_t)NK * 384 * 4);
  float* vbuf = (float*)alloc((size_t)NK * 384 * 4);
  float* aout = (float*)alloc((size_t)NQ * 384 * 4);
  float* tgt2 = (float*)alloc((size_t)NQ * 384 * 4);
  float* h1f  = (float*)alloc((size_t)NQ * 384 * 4);   // [(n*3+c)][128] fp32
  u16* kh   = (u16*)alloc((size_t)NK * 384 * 2);       // fp16 K (attn gather)
  u16* vh   = (u16*)alloc((size_t)NK * 384 * 2);       // fp16 V (attn gather)
  u16* h1h  = (u16*)alloc((size_t)6144 * 128 * 2);     // fp16 plane
  u16* W1h  = (u16*)alloc((size_t)DFF * 128 * 2);      // fp16
  u16* Wdh  = (u16*)alloc((size_t)DFF * DFF * 2);      // fp16
  u16* W2h  = (u16*)alloc((size_t)128 * DFF * 2);      // fp16
  u16* Ff16 = (u16*)alloc((size_t)6144 * DFF * 2);     // [(n*3+c)][dff] fp16 (W1 out)
  u16* Dm   = (u16*)alloc((size_t)6144 * DFF * 2);     // fp16 (Wd out)
  u16* Fp   = (u16*)alloc((size_t)6144 * DFF * 2);     // fp16 (vnrelu out)
  float* Gp = (float*)Ff16;  // alias: Ff16 (25.2 MB) dead after vnrelu reads it;
                             // W2-gemm reads Fp and writes Gp — no overlap.
  int* dflag = (int*)alloc(256);

  detect_i64_kernel<<<1, 64, 0, stream>>>(ipair, dflag);
  quantf16_kernel<<<256, 256, 0, stream>>>(W1, W1h, DFF * 128);
  quantf16_kernel<<<2048, 256, 0, stream>>>(Wd, Wdh, DFF * DFF);
  quantf16_kernel<<<256, 256, 0, stream>>>(W2, W2h, 128 * DFF);

  proj_kernel<<<NQ / 2, 256, 0, stream>>>(tgt, Wq, q, nullptr);
  proj_kernel<<<NK / 2, 256, 0, stream>>>(mem, Wk, kbuf, kh);
  proj_kernel<<<NK / 2, 256, 0, stream>>>(mem, Wv, vbuf, vh);
  attn_kernel<<<NQ, 512, 0, stream>>>(q, kh, vh, ipair, kbc, ipb, dflag, aout);
  proj_kernel<<<NQ / 2, 256, 0, stream>>>(aout, Wo, tgt2, nullptr);
  ln1_kernel<<<NQ, 128, 0, stream>>>(tgt, tgt2, ln1g, ln1b, h1f, h1h);

  // F = h1 * W1^T   (M=6144, N=2048, K=128), fp16, 128^2 structure
  gemm_f16<0><<<dim3(48, 16, 1), 256, 0, stream>>>(h1h, W1h, Ff16, 6144, DFF, 128);
  // D = F * Wd^T    (M=6144, N=2048, K=2048), fp16, 256^2 phase-scheduled
  gemm_f16_256<<<dim3(24, 8, 1), 512, 0, stream>>>(Ff16, Wdh, Dm, 6144, DFF, DFF);
  // F' = vnrelu(F, D) -> Fp, out-of-place, x8 vectorized
  vnrelu8_kernel<<<(NQ * DFF) / (256 * 8), 256, 0, stream>>>(Ff16, Dm, Fp);
  // Gp partials = F' * W2^T  (M=6144, N=128, K=2048), split-K=8, fp32 partials
  gemm_f16<1><<<dim3(48, 1, SPLITS), 256, 0, stream>>>(Fp, W2h, Gp, 6144, 128, DFF);
  ln2_kernel<<<NQ, 128, 0, stream>>>(h1f, Gp, ln2g, ln2b, out);
}